// Round 5
// baseline (177.176 us; speedup 1.0000x reference)
//
#include <hip/hip_runtime.h>

typedef __bf16 bf16x8 __attribute__((ext_vector_type(8)));
typedef float f32x4 __attribute__((ext_vector_type(4)));
typedef float f32x16 __attribute__((ext_vector_type(16)));
typedef unsigned short u16x8 __attribute__((ext_vector_type(8)));
typedef unsigned short u16x4 __attribute__((ext_vector_type(4)));
typedef unsigned u32x4 __attribute__((ext_vector_type(4)));

#define BB 4
#define TT 2048
#define CC 1024
#define HH 16
#define DD 64

__device__ __forceinline__ unsigned short f2bf(float f){
  unsigned u = __builtin_bit_cast(unsigned, f);
  u += 0x7FFFu + ((u >> 16) & 1u);
  return (unsigned short)(u >> 16);
}
__device__ __forceinline__ bf16x8 as_bf(u16x8 v){ return __builtin_bit_cast(bf16x8, v); }
__device__ __forceinline__ unsigned cvt_pk(float lo, float hi){
  unsigned r; asm("v_cvt_pk_bf16_f32 %0, %1, %2" : "=v"(r) : "v"(lo), "v"(hi)); return r;
}
__device__ __forceinline__ void pl32swap(unsigned &a, unsigned &b){
  asm("v_permlane32_swap_b32 %0, %1" : "+v"(a), "+v"(b));
}
__device__ __forceinline__ float ex2(float x){
#if __has_builtin(__builtin_amdgcn_exp2f)
  return __builtin_amdgcn_exp2f(x);
#else
  return __expf(x * 0.6931471805599453f);
#endif
}

// all 5 fp32->bf16 conversions in one launch
__global__ __launch_bounds__(256) void cvt_all(const float* __restrict__ x,
                                               const float* __restrict__ Wk,
                                               const float* __restrict__ Wq,
                                               const float* __restrict__ Wv,
                                               const float* __restrict__ Wp,
                                               unsigned short* __restrict__ xb,
                                               unsigned short* __restrict__ wb){
  const int i = blockIdx.x * 256 + threadIdx.x;           // one float4 per thread
  constexpr int EX = (BB*TT*CC)/4;                        // 2,097,152
  const float* src; unsigned short* dst; int off;
  if (i < EX){ src = x; dst = xb; off = i; }
  else {
    const int j = i - EX;
    const int wsel = j >> 18;                             // Wn/4 = 2^18
    off = j & 262143;
    src = (wsel==0) ? Wk : (wsel==1) ? Wq : (wsel==2) ? Wv : Wp;
    dst = wb + ((size_t)wsel << 20);                      // Wn = 2^20
  }
  const float4 f = ((const float4*)src)[off];
  u16x4 o; o.x = f2bf(f.x); o.y = f2bf(f.y); o.z = f2bf(f.z); o.w = f2bf(f.w);
  ((u16x4*)dst)[off] = o;
}

// C = A @ B^T, A: 8192xK row-major bf16, B: (NX*128)xK row-major bf16.
// QKV=true: bf16 out into o0/o1/o2 (K,Q,V) with Q scaled by log2e/8. else f32 out o0.
template<int NX, bool QKV>
__global__ __launch_bounds__(256) void gemm128(const unsigned short* __restrict__ A,
                                               const unsigned short* __restrict__ Bm,
                                               void* __restrict__ o0, void* __restrict__ o1,
                                               void* __restrict__ o2){
  constexpr int K = 1024;
  constexpr int NWG = NX * 64;
  __shared__ __align__(16) unsigned short As[128*64];
  __shared__ __align__(16) unsigned short Bs[128*64];
  const int tid = threadIdx.x;
  const int flat = blockIdx.y * NX + blockIdx.x;
  const int swz = (flat & 7) * (NWG / 8) + (flat >> 3);   // bijective XCD swizzle
  const int n0 = (swz % NX) * 128;
  const int m0 = (swz / NX) * 128;
  const int w = tid >> 6, lane = tid & 63, l15 = lane & 15, g = lane >> 4;
  const int wm = (w >> 1) * 64, wn = (w & 1) * 64;

  f32x4 acc[4][4] = {};

  for (int k0 = 0; k0 < K; k0 += 64){
    #pragma unroll
    for (int i = 0; i < 4; ++i){
      const int p = i*256 + tid;
      const int r = p >> 3, c = p & 7;
      const int gc = c ^ (r & 7);
      __builtin_amdgcn_global_load_lds(
        (const __attribute__((address_space(1))) void*)(A + (size_t)(m0 + r)*K + k0 + gc*8),
        (__attribute__((address_space(3))) void*)(As + p*8), 16, 0, 0);
    }
    #pragma unroll
    for (int i = 0; i < 4; ++i){
      const int p = i*256 + tid;
      const int r = p >> 3, c = p & 7;
      const int gc = c ^ (r & 7);
      __builtin_amdgcn_global_load_lds(
        (const __attribute__((address_space(1))) void*)(Bm + (size_t)(n0 + r)*K + k0 + gc*8),
        (__attribute__((address_space(3))) void*)(Bs + p*8), 16, 0, 0);
    }
    __syncthreads();

    bf16x8 af[2][4], bfr[2][4];
    #pragma unroll
    for (int ks = 0; ks < 2; ++ks){
      #pragma unroll
      for (int m = 0; m < 4; ++m){
        const int R = wm + m*16 + l15;
        const int c = (ks*4 + g) ^ (R & 7);
        af[ks][m] = as_bf(*(const u16x8*)(As + R*64 + c*8));
      }
      #pragma unroll
      for (int n = 0; n < 4; ++n){
        const int R = wn + n*16 + l15;
        const int c = (ks*4 + g) ^ (R & 7);
        bfr[ks][n] = as_bf(*(const u16x8*)(Bs + R*64 + c*8));
      }
    }
    #pragma unroll
    for (int ks = 0; ks < 2; ++ks)
      #pragma unroll
      for (int m = 0; m < 4; ++m)
        #pragma unroll
        for (int n = 0; n < 4; ++n)
          acc[m][n] = __builtin_amdgcn_mfma_f32_16x16x32_bf16(af[ks][m], bfr[ks][n], acc[m][n], 0, 0, 0);
    __syncthreads();
  }

  const int tsel = n0 >> 10;                    // uniform per block (QKV only)
  const float sc = (QKV && tsel == 1) ? 0.18033688011112042f : 1.0f;  // log2(e)/8
  unsigned short* outb = nullptr;
  if (QKV) outb = (unsigned short*)(tsel == 0 ? o0 : tsel == 1 ? o1 : o2);

  #pragma unroll
  for (int m = 0; m < 4; ++m)
    #pragma unroll
    for (int n = 0; n < 4; ++n)
      #pragma unroll
      for (int r = 0; r < 4; ++r){
        const int row = m0 + wm + m*16 + g*4 + r;
        const int col = n0 + wn + n*16 + l15;
        const float v = acc[m][n][r];
        if (QKV) outb[(size_t)row*1024 + (col & 1023)] = f2bf(v * sc);
        else     ((float*)o0)[(size_t)row*1024 + col] = v;
      }
}

// V [B,T,C] (head slice) -> Vt [B*H][D][T], k-chunks XOR-swizzled within each 64-tile
__global__ __launch_bounds__(256) void transpose_v(const unsigned short* __restrict__ V,
                                                   unsigned short* __restrict__ Vt){
  __shared__ unsigned short Ts[64*72];
  const int kt = blockIdx.x, bh = blockIdx.y;
  const int b = bh >> 4, h = bh & 15;
  const int tid = threadIdx.x;
  #pragma unroll
  for (int i = 0; i < 2; ++i){
    const int p = i*256 + tid, r = p >> 3, c = p & 7;
    *(u16x8*)(Ts + r*72 + c*8) =
      *(const u16x8*)(V + (size_t)b*TT*CC + (size_t)(kt*64 + r)*CC + h*DD + c*8);
  }
  __syncthreads();
  #pragma unroll
  for (int i = 0; i < 2; ++i){
    const int p = i*256 + tid, d = p >> 3, c = p & 7;
    u16x8 v;
    #pragma unroll
    for (int j = 0; j < 8; ++j) v[j] = Ts[(c*8 + j)*72 + d];
    *(u16x8*)(Vt + ((size_t)bh*DD + d)*TT + (size_t)kt*64 + ((c ^ (d & 7))*8)) = v;
  }
}

// Causal flash attention, swapped-QK 32x32, 4 waves x 64 q-rows (2 groups/wave).
// Q,K: [B,T,C] bf16 (Q pre-scaled by log2e/8); Vt: [B*H][D][T] swizzled; Y: [B,T,C] bf16
__global__ __launch_bounds__(256, 2) void attn3(const unsigned short* __restrict__ Q,
                                                const unsigned short* __restrict__ Km,
                                                const unsigned short* __restrict__ Vt,
                                                unsigned short* __restrict__ Y){
  __shared__ __align__(16) unsigned short Ks[4][64*64];
  __shared__ __align__(16) unsigned short Vs[4][64*64];
  const int bh = blockIdx.x, b = bh >> 4, hd = bh & 15;
  const int qt = 7 - blockIdx.y;                  // heavy strips dispatch first
  const int tid = threadIdx.x;
  const int w = tid >> 6, lane = tid & 63, l31 = lane & 31, hi = lane >> 5;
  const int nkt = 4*qt + 4;
  const int qbase = qt*256 + w*64;                // wave's 64 q-rows
  const int tD = 4*qt + w;                        // wave's last (diagonal) tile
  const int qga = qbase + l31, qgb = qbase + 32 + l31;

  const unsigned short* Ksrc = Km + (size_t)b*TT*CC + hd*DD;
  const unsigned short* Vsrc = Vt + (size_t)bh*DD*TT;

  auto stage = [&](int buf, int kt){
    #pragma unroll
    for (int i = 0; i < 2; ++i){
      const int rr = (tid >> 3) + i*32, c = tid & 7;
      const int gc = c ^ (rr & 7);
      __builtin_amdgcn_global_load_lds(
        (const __attribute__((address_space(1))) void*)(Ksrc + (size_t)(kt*64 + rr)*CC + gc*8),
        (__attribute__((address_space(3))) void*)(&Ks[buf][(i*256 + tid)*8]), 16, 0, 0);
      __builtin_amdgcn_global_load_lds(
        (const __attribute__((address_space(1))) void*)(Vsrc + (size_t)rr*TT + (size_t)kt*64 + c*8),
        (__attribute__((address_space(3))) void*)(&Vs[buf][(i*256 + tid)*8]), 16, 0, 0);
    }
  };

  stage(0, 0);
  stage(1, 1);          // nkt >= 4 always

  // Q fragments (B-operand): q = l31 (+32 for group B), d = 16*ds + 8*hi + j
  const unsigned short* qra = Q + ((size_t)b*TT + qbase + l31)*CC + hd*DD;
  bf16x8 qfA[4], qfB[4];
  #pragma unroll
  for (int ds = 0; ds < 4; ++ds){
    qfA[ds] = as_bf(*(const u16x8*)(qra + 16*ds + 8*hi));
    qfB[ds] = as_bf(*(const u16x8*)(qra + 32*CC + 16*ds + 8*hi));
  }

  // LDS fragment offsets (elements); same for K and V tiles, +2048 for rows 32..63
  int koff[4];
  #pragma unroll
  for (int ds = 0; ds < 4; ++ds)
    koff[ds] = l31*64 + (((2*ds + hi) ^ (l31 & 7)) * 8);

  float mA = -1e30f, lA = 0.f, mB = -1e30f, lB = 0.f;
  f32x16 yA0 = {}, yA1 = {}, yB0 = {}, yB1 = {};

  auto sm = [&](f32x16& s0, f32x16& s1, float& m_, float& l_, f32x16& y0, f32x16& y1){
    float tm[8];
    #pragma unroll
    for (int r = 0; r < 8; ++r) tm[r] = fmaxf(fmaxf(s0[r], s0[r+8]), fmaxf(s1[r], s1[r+8]));
    #pragma unroll
    for (int r = 0; r < 4; ++r) tm[r] = fmaxf(tm[r], tm[r+4]);
    float pmax = fmaxf(fmaxf(tm[0], tm[2]), fmaxf(tm[1], tm[3]));
    pmax = fmaxf(pmax, __shfl_xor(pmax, 32));
    if (!__all(pmax <= m_ + 8.f)){
      const float mnew = fmaxf(m_, pmax);
      const float alpha = ex2(m_ - mnew);
      l_ *= alpha;
      #pragma unroll
      for (int r = 0; r < 16; ++r){
        const float ar = __shfl(alpha, (r & 3) + 8*(r >> 2) + 4*hi);
        y0[r] *= ar; y1[r] *= ar;
      }
      m_ = mnew;
    }
    #pragma unroll
    for (int r = 0; r < 16; ++r) s0[r] = ex2(s0[r] - m_);
    #pragma unroll
    for (int r = 0; r < 16; ++r) s1[r] = ex2(s1[r] - m_);
    float ts[8];
    #pragma unroll
    for (int r = 0; r < 8; ++r) ts[r] = (s0[r] + s0[r+8]) + (s1[r] + s1[r+8]);
    #pragma unroll
    for (int r = 0; r < 4; ++r) ts[r] += ts[r+4];
    float rs = (ts[0] + ts[2]) + (ts[1] + ts[3]);
    rs += __shfl_xor(rs, 32);
    l_ += rs;
  };

  auto pack = [&](const f32x16& s0, const f32x16& s1, bf16x8* pa){
    #pragma unroll
    for (int m = 0; m < 4; ++m){
      const f32x16& c = (m < 2) ? s0 : s1;
      const int bx = (m & 1) * 8;
      unsigned A0 = cvt_pk(c[bx+0], c[bx+1]);
      unsigned B0 = cvt_pk(c[bx+4], c[bx+5]);
      pl32swap(A0, B0);
      unsigned A1 = cvt_pk(c[bx+2], c[bx+3]);
      unsigned B1 = cvt_pk(c[bx+6], c[bx+7]);
      pl32swap(A1, B1);
      u32x4 pw; pw.x = A0; pw.y = A1; pw.z = B0; pw.w = B1;
      pa[m] = __builtin_bit_cast(bf16x8, pw);
    }
  };

  for (int t = 0; t < nkt; ++t){
    if (t + 2 < nkt){
      stage((t + 2) & 3, t + 2);
      asm volatile("s_waitcnt vmcnt(8)" ::: "memory");     // drain tile t's 4 loads
    } else if (t + 1 < nkt){
      asm volatile("s_waitcnt vmcnt(4)" ::: "memory");
    } else {
      asm volatile("s_waitcnt vmcnt(0)" ::: "memory");
    }
    __builtin_amdgcn_s_barrier();
    if (t > tD) continue;                                   // stage+barrier still run

    const unsigned short* Kp = &Ks[t & 3][0];
    const unsigned short* Vp = &Vs[t & 3][0];

    // S^T = K . Q^T for both q-groups; each K-frag feeds 2 MFMAs
    f32x16 sA0 = {}, sA1 = {}, sB0 = {}, sB1 = {};
    __builtin_amdgcn_s_setprio(1);
    #pragma unroll
    for (int ds = 0; ds < 4; ++ds){
      bf16x8 kf0 = as_bf(*(const u16x8*)(Kp + koff[ds]));
      sA0 = __builtin_amdgcn_mfma_f32_32x32x16_bf16(kf0, qfA[ds], sA0, 0, 0, 0);
      sB0 = __builtin_amdgcn_mfma_f32_32x32x16_bf16(kf0, qfB[ds], sB0, 0, 0, 0);
      bf16x8 kf1 = as_bf(*(const u16x8*)(Kp + koff[ds] + 2048));
      sA1 = __builtin_amdgcn_mfma_f32_32x32x16_bf16(kf1, qfA[ds], sA1, 0, 0, 0);
      sB1 = __builtin_amdgcn_mfma_f32_32x32x16_bf16(kf1, qfB[ds], sB1, 0, 0, 0);
    }
    __builtin_amdgcn_s_setprio(0);

    if (t == tD){            // diagonal tile: causal mask (k_g > q_g)
      const int kb0 = t*64;
      #pragma unroll
      for (int r = 0; r < 16; ++r){
        const int kr = (r & 3) + 8*(r >> 2) + 4*hi;
        if (kb0 + kr      > qga) sA0[r] = -1e30f;
        if (kb0 + 32 + kr > qga) sA1[r] = -1e30f;
        if (kb0 + kr      > qgb) sB0[r] = -1e30f;
        if (kb0 + 32 + kr > qgb) sB1[r] = -1e30f;
      }
    }

    sm(sA0, sA1, mA, lA, yA0, yA1);
    sm(sB0, sB1, mB, lB, yB0, yB1);

    bf16x8 paA[4], paB[4];
    pack(sA0, sA1, paA);
    pack(sB0, sB1, paB);

    // Y += P @ V ; each V-frag feeds 2 MFMAs
    __builtin_amdgcn_s_setprio(1);
    #pragma unroll
    for (int m = 0; m < 4; ++m){
      bf16x8 vf0 = as_bf(*(const u16x8*)(Vp + koff[m]));
      yA0 = __builtin_amdgcn_mfma_f32_32x32x16_bf16(paA[m], vf0, yA0, 0, 0, 0);
      yB0 = __builtin_amdgcn_mfma_f32_32x32x16_bf16(paB[m], vf0, yB0, 0, 0, 0);
      bf16x8 vf1 = as_bf(*(const u16x8*)(Vp + koff[m] + 2048));
      yA1 = __builtin_amdgcn_mfma_f32_32x32x16_bf16(paA[m], vf1, yA1, 0, 0, 0);
      yB1 = __builtin_amdgcn_mfma_f32_32x32x16_bf16(paB[m], vf1, yB1, 0, 0, 0);
    }
    __builtin_amdgcn_s_setprio(0);
  }

  auto wr = [&](const f32x16& y0, const f32x16& y1, float l_, int qb){
    const float linv = 1.f / l_;
    #pragma unroll
    for (int r = 0; r < 16; ++r){
      const int qlr = (r & 3) + 8*(r >> 2) + 4*hi;
      const float lr = __shfl(linv, qlr);
      unsigned short* yp = Y + ((size_t)b*TT + qb + qlr)*CC + hd*DD + l31;
      yp[0]  = f2bf(y0[r] * lr);
      yp[32] = f2bf(y1[r] * lr);
    }
  };
  wr(yA0, yA1, lA, qbase);
  wr(yB0, yB1, lB, qbase + 32);
}

extern "C" void kernel_launch(void* const* d_in, const int* in_sizes, int n_in,
                              void* d_out, int out_size, void* d_ws, size_t ws_size,
                              hipStream_t stream){
  const float* x  = (const float*)d_in[0];
  const float* Wk = (const float*)d_in[1];
  const float* Wq = (const float*)d_in[2];
  const float* Wv = (const float*)d_in[3];
  const float* Wp = (const float*)d_in[4];

  const size_t E  = (size_t)BB*TT*CC;
  const size_t Wn = (size_t)CC*CC;
  unsigned short* ws  = (unsigned short*)d_ws;
  unsigned short* xb  = ws;                 // reused as yb after attention
  unsigned short* wkb = xb  + E;            // wkb,wqb,wvb contiguous = B[3072][1024]
  unsigned short* wqb = wkb + Wn;
  unsigned short* wvb = wqb + Wn;
  unsigned short* wpb = wvb + Wn;
  unsigned short* qb  = wpb + Wn;
  unsigned short* kb  = qb  + E;
  unsigned short* vb  = kb  + E;
  unsigned short* vt  = vb  + E;

  cvt_all<<<12288, 256, 0, stream>>>(x, Wk, Wq, Wv, Wp, xb, wkb);

  // fused QKV: B = [Wk; Wq; Wv] (3072x1024), outputs kb/qb/vb, Q scaled by log2e/8
  gemm128<24, true><<<dim3(24, 64), 256, 0, stream>>>(xb, wkb, kb, qb, vb);

  transpose_v<<<dim3(TT/64, BB*HH), 256, 0, stream>>>(vb, vt);

  unsigned short* yb = xb;
  attn3<<<dim3(BB*HH, TT/256), 256, 0, stream>>>(qb, kb, vt, yb);

  gemm128<8, false><<<dim3(8, 64), 256, 0, stream>>>(yb, wpb, (float*)d_out, nullptr, nullptr);
}

// Round 6
// 163.530 us; speedup vs baseline: 1.0834x; 1.0834x over previous
//
#include <hip/hip_runtime.h>

typedef __bf16 bf16x8 __attribute__((ext_vector_type(8)));
typedef float f32x4 __attribute__((ext_vector_type(4)));
typedef float f32x16 __attribute__((ext_vector_type(16)));
typedef unsigned short u16x8 __attribute__((ext_vector_type(8)));
typedef unsigned short u16x4 __attribute__((ext_vector_type(4)));
typedef unsigned u32x4 __attribute__((ext_vector_type(4)));

#define BB 4
#define TT 2048
#define CC 1024
#define HH 16
#define DD 64

__device__ __forceinline__ unsigned short f2bf(float f){
  unsigned u = __builtin_bit_cast(unsigned, f);
  u += 0x7FFFu + ((u >> 16) & 1u);
  return (unsigned short)(u >> 16);
}
__device__ __forceinline__ bf16x8 as_bf(u16x8 v){ return __builtin_bit_cast(bf16x8, v); }
__device__ __forceinline__ unsigned cvt_pk(float lo, float hi){
  unsigned r; asm("v_cvt_pk_bf16_f32 %0, %1, %2" : "=v"(r) : "v"(lo), "v"(hi)); return r;
}
__device__ __forceinline__ void pl32swap(unsigned &a, unsigned &b){
  asm("v_permlane32_swap_b32 %0, %1" : "+v"(a), "+v"(b));
}
__device__ __forceinline__ float ex2(float x){
#if __has_builtin(__builtin_amdgcn_exp2f)
  return __builtin_amdgcn_exp2f(x);
#else
  return __expf(x * 0.6931471805599453f);
#endif
}

// all 5 fp32->bf16 conversions in one launch
__global__ __launch_bounds__(256) void cvt_all(const float* __restrict__ x,
                                               const float* __restrict__ Wk,
                                               const float* __restrict__ Wq,
                                               const float* __restrict__ Wv,
                                               const float* __restrict__ Wp,
                                               unsigned short* __restrict__ xb,
                                               unsigned short* __restrict__ wb){
  const int i = blockIdx.x * 256 + threadIdx.x;           // one float4 per thread
  constexpr int EX = (BB*TT*CC)/4;                        // 2,097,152
  const float* src; unsigned short* dst; int off;
  if (i < EX){ src = x; dst = xb; off = i; }
  else {
    const int j = i - EX;
    const int wsel = j >> 18;                             // Wn/4 = 2^18
    off = j & 262143;
    src = (wsel==0) ? Wk : (wsel==1) ? Wq : (wsel==2) ? Wv : Wp;
    dst = wb + ((size_t)wsel << 20);                      // Wn = 2^20
  }
  const float4 f = ((const float4*)src)[off];
  u16x4 o; o.x = f2bf(f.x); o.y = f2bf(f.y); o.z = f2bf(f.z); o.w = f2bf(f.w);
  ((u16x4*)dst)[off] = o;
}

// C = A @ B^T, A: 8192xK row-major bf16, B: (NX*128)xK row-major bf16.
// Double-buffered LDS pipeline: stage(kt+1) issued before compute(kt), counted vmcnt.
// QKV=true: bf16 out into o0/o1/o2 (K,Q,V) with Q scaled by log2e/8. else f32 out o0.
template<int NX, bool QKV>
__global__ __launch_bounds__(256) void gemm128(const unsigned short* __restrict__ A,
                                               const unsigned short* __restrict__ Bm,
                                               void* __restrict__ o0, void* __restrict__ o1,
                                               void* __restrict__ o2){
  constexpr int K = 1024;
  constexpr int NKT = K / 64;                             // 16
  constexpr int NWG = NX * 64;
  __shared__ __align__(16) unsigned short As[2][128*64];
  __shared__ __align__(16) unsigned short Bs[2][128*64];
  const int tid = threadIdx.x;
  const int flat = blockIdx.y * NX + blockIdx.x;
  const int swz = (flat & 7) * (NWG / 8) + (flat >> 3);   // bijective XCD swizzle
  const int n0 = (swz % NX) * 128;
  const int m0 = (swz / NX) * 128;
  const int w = tid >> 6, lane = tid & 63, l15 = lane & 15, g = lane >> 4;
  const int wm = (w >> 1) * 64, wn = (w & 1) * 64;

  auto stage = [&](int d, int k0){
    #pragma unroll
    for (int i = 0; i < 4; ++i){
      const int p = i*256 + tid;
      const int r = p >> 3, c = p & 7;
      const int gc = c ^ (r & 7);
      __builtin_amdgcn_global_load_lds(
        (const __attribute__((address_space(1))) void*)(A + (size_t)(m0 + r)*K + k0 + gc*8),
        (__attribute__((address_space(3))) void*)(&As[d][p*8]), 16, 0, 0);
    }
    #pragma unroll
    for (int i = 0; i < 4; ++i){
      const int p = i*256 + tid;
      const int r = p >> 3, c = p & 7;
      const int gc = c ^ (r & 7);
      __builtin_amdgcn_global_load_lds(
        (const __attribute__((address_space(1))) void*)(Bm + (size_t)(n0 + r)*K + k0 + gc*8),
        (__attribute__((address_space(3))) void*)(&Bs[d][p*8]), 16, 0, 0);
    }
  };

  f32x4 acc[4][4] = {};
  stage(0, 0);

  for (int kt = 0; kt < NKT; ++kt){
    const int d = kt & 1;
    if (kt + 1 < NKT){
      stage(d ^ 1, (kt + 1) * 64);                        // prefetch next tile
      asm volatile("s_waitcnt vmcnt(8)" ::: "memory");    // tile kt landed, kt+1 in flight
    } else {
      asm volatile("s_waitcnt vmcnt(0)" ::: "memory");
    }
    __builtin_amdgcn_s_barrier();

    bf16x8 af[2][4], bfr[2][4];
    #pragma unroll
    for (int ks = 0; ks < 2; ++ks){
      #pragma unroll
      for (int m = 0; m < 4; ++m){
        const int R = wm + m*16 + l15;
        const int c = (ks*4 + g) ^ (R & 7);
        af[ks][m] = as_bf(*(const u16x8*)(&As[d][R*64 + c*8]));
      }
      #pragma unroll
      for (int n = 0; n < 4; ++n){
        const int R = wn + n*16 + l15;
        const int c = (ks*4 + g) ^ (R & 7);
        bfr[ks][n] = as_bf(*(const u16x8*)(&Bs[d][R*64 + c*8]));
      }
    }
    #pragma unroll
    for (int ks = 0; ks < 2; ++ks)
      #pragma unroll
      for (int m = 0; m < 4; ++m)
        #pragma unroll
        for (int n = 0; n < 4; ++n)
          acc[m][n] = __builtin_amdgcn_mfma_f32_16x16x32_bf16(af[ks][m], bfr[ks][n], acc[m][n], 0, 0, 0);

    __builtin_amdgcn_s_barrier();                         // reads done before buf reuse
  }

  const int tsel = n0 >> 10;                    // uniform per block (QKV only)
  const float sc = (QKV && tsel == 1) ? 0.18033688011112042f : 1.0f;  // log2(e)/8
  unsigned short* outb = nullptr;
  if (QKV) outb = (unsigned short*)(tsel == 0 ? o0 : tsel == 1 ? o1 : o2);

  #pragma unroll
  for (int m = 0; m < 4; ++m)
    #pragma unroll
    for (int n = 0; n < 4; ++n)
      #pragma unroll
      for (int r = 0; r < 4; ++r){
        const int row = m0 + wm + m*16 + g*4 + r;
        const int col = n0 + wn + n*16 + l15;
        const float v = acc[m][n][r];
        if (QKV) outb[(size_t)row*1024 + (col & 1023)] = f2bf(v * sc);
        else     ((float*)o0)[(size_t)row*1024 + col] = v;
      }
}

// V [B,T,C] (head slice) -> Vt [B*H][D][T], k-chunks XOR-swizzled within each 64-tile
__global__ __launch_bounds__(256) void transpose_v(const unsigned short* __restrict__ V,
                                                   unsigned short* __restrict__ Vt){
  __shared__ unsigned short Ts[64*72];
  const int kt = blockIdx.x, bh = blockIdx.y;
  const int b = bh >> 4, h = bh & 15;
  const int tid = threadIdx.x;
  #pragma unroll
  for (int i = 0; i < 2; ++i){
    const int p = i*256 + tid, r = p >> 3, c = p & 7;
    *(u16x8*)(Ts + r*72 + c*8) =
      *(const u16x8*)(V + (size_t)b*TT*CC + (size_t)(kt*64 + r)*CC + h*DD + c*8);
  }
  __syncthreads();
  #pragma unroll
  for (int i = 0; i < 2; ++i){
    const int p = i*256 + tid, d = p >> 3, c = p & 7;
    u16x8 v;
    #pragma unroll
    for (int j = 0; j < 8; ++j) v[j] = Ts[(c*8 + j)*72 + d];
    *(u16x8*)(Vt + ((size_t)bh*DD + d)*TT + (size_t)kt*64 + ((c ^ (d & 7))*8)) = v;
  }
}

// Causal flash attention, swapped-QK 32x32, 8 waves x 32 q-rows = 256 q-rows/block.
// Balanced strip pairing: co-resident blocks (i, i+256) -> (heavy, light) strips.
// Q,K: [B,T,C] bf16 (Q pre-scaled by log2e/8); Vt: [B*H][D][T] swizzled; Y: [B,T,C] bf16
__global__ __launch_bounds__(512, 4) void attn2(const unsigned short* __restrict__ Q,
                                                const unsigned short* __restrict__ Km,
                                                const unsigned short* __restrict__ Vt,
                                                unsigned short* __restrict__ Y){
  __shared__ __align__(16) unsigned short Ks[3][64*64];
  __shared__ __align__(16) unsigned short Vs[3][64*64];
  const int bh = blockIdx.x, b = bh >> 4, h = bh & 15;
  const int yq = blockIdx.y;
  const int qt = (yq < 4) ? (7 - yq) : (yq - 4);  // pairs (7,0),(6,1),(5,2),(4,3) per CU
  const int tid = threadIdx.x;
  const int w = tid >> 6, lane = tid & 63, l31 = lane & 31, hi = lane >> 5;
  const int q0 = qt * 256;
  const int wq0 = q0 + w * 32;
  const int wqmax = wq0 + 31;
  const int nkt = 4 * qt + 4;
  const int qg = wq0 + l31;

  const unsigned short* Ksrc = Km + (size_t)b*TT*CC + h*DD;
  const unsigned short* Vsrc = Vt + (size_t)bh*DD*TT;

  auto stage = [&](int buf, int kt){
    const int r = tid >> 3, c = tid & 7;
    const int gc = c ^ (r & 7);
    __builtin_amdgcn_global_load_lds(
      (const __attribute__((address_space(1))) void*)(Ksrc + (size_t)(kt*64 + r)*CC + gc*8),
      (__attribute__((address_space(3))) void*)(&Ks[buf][tid*8]), 16, 0, 0);
    __builtin_amdgcn_global_load_lds(
      (const __attribute__((address_space(1))) void*)(Vsrc + (size_t)r*TT + (size_t)kt*64 + c*8),
      (__attribute__((address_space(3))) void*)(&Vs[buf][tid*8]), 16, 0, 0);
  };

  stage(0, 0);

  // Q fragments (B-operand): q = l31, d = 16*ds + 8*hi + j
  const unsigned short* qrow = Q + ((size_t)b*TT + wq0 + l31)*CC + h*DD;
  bf16x8 qf[4];
  #pragma unroll
  for (int ds = 0; ds < 4; ++ds)
    qf[ds] = as_bf(*(const u16x8*)(qrow + 16*ds + 8*hi));

  // LDS fragment offsets (elements); same for K and V tiles, +2048 for rows 32..63
  int koff[4];
  #pragma unroll
  for (int ds = 0; ds < 4; ++ds)
    koff[ds] = l31*64 + (((2*ds + hi) ^ (l31 & 7)) * 8);

  float m_ = -1e30f, l_ = 0.f;
  f32x16 y0 = {}, y1 = {};

  int cb = 0;
  for (int t = 0; t < nkt; ++t){
    const int nx = (cb == 2) ? 0 : cb + 1;
    if (t + 1 < nkt){
      stage(nx, t + 1);
      asm volatile("s_waitcnt vmcnt(2)" ::: "memory");
    } else {
      asm volatile("s_waitcnt vmcnt(0)" ::: "memory");
    }
    __builtin_amdgcn_s_barrier();

    if (t*64 <= wqmax){
      const unsigned short* Kp = &Ks[cb][0];
      const unsigned short* Vp = &Vs[cb][0];

      // S^T = K . Q^T : lane holds q-col (l31), 32 k-rows across regs+hi
      f32x16 s0 = {}, s1 = {};
      __builtin_amdgcn_s_setprio(1);
      #pragma unroll
      for (int ds = 0; ds < 4; ++ds){
        bf16x8 kf0 = as_bf(*(const u16x8*)(Kp + koff[ds]));
        s0 = __builtin_amdgcn_mfma_f32_32x32x16_bf16(kf0, qf[ds], s0, 0, 0, 0);
        bf16x8 kf1 = as_bf(*(const u16x8*)(Kp + koff[ds] + 2048));
        s1 = __builtin_amdgcn_mfma_f32_32x32x16_bf16(kf1, qf[ds], s1, 0, 0, 0);
      }
      __builtin_amdgcn_s_setprio(0);

      if (t*64 + 63 > wq0){   // boundary tiles: causal mask (k_g > q_g)
        const int kb0 = t*64;
        #pragma unroll
        for (int r = 0; r < 16; ++r){
          const int kr = (r & 3) + 8*(r >> 2) + 4*hi;
          if (kb0 + kr      > qg) s0[r] = -1e30f;
          if (kb0 + 32 + kr > qg) s1[r] = -1e30f;
        }
      }

      // tree max over 32 scores, then lane-pair merge
      float tm[8];
      #pragma unroll
      for (int r = 0; r < 8; ++r) tm[r] = fmaxf(fmaxf(s0[r], s0[r+8]), fmaxf(s1[r], s1[r+8]));
      #pragma unroll
      for (int r = 0; r < 4; ++r) tm[r] = fmaxf(tm[r], tm[r+4]);
      float pmax = fmaxf(fmaxf(tm[0], tm[2]), fmaxf(tm[1], tm[3]));
      pmax = fmaxf(pmax, __shfl_xor(pmax, 32));

      // defer-max rescale (log2 domain, THR=8 -> P <= 256)
      if (!__all(pmax <= m_ + 8.f)){
        const float mnew = fmaxf(m_, pmax);
        const float alpha = ex2(m_ - mnew);
        l_ *= alpha;
        #pragma unroll
        for (int r = 0; r < 16; ++r){
          const float ar = __shfl(alpha, (r & 3) + 8*(r >> 2) + 4*hi);
          y0[r] *= ar; y1[r] *= ar;
        }
        m_ = mnew;
      }

      #pragma unroll
      for (int r = 0; r < 16; ++r) s0[r] = ex2(s0[r] - m_);
      #pragma unroll
      for (int r = 0; r < 16; ++r) s1[r] = ex2(s1[r] - m_);
      float ts[8];
      #pragma unroll
      for (int r = 0; r < 8; ++r) ts[r] = (s0[r] + s0[r+8]) + (s1[r] + s1[r+8]);
      #pragma unroll
      for (int r = 0; r < 4; ++r) ts[r] += ts[r+4];
      float rs = (ts[0] + ts[2]) + (ts[1] + ts[3]);
      rs += __shfl_xor(rs, 32);
      l_ += rs;

      // P -> A-frags (cvt_pk + permlane32_swap), fused with PV MFMA
      __builtin_amdgcn_s_setprio(1);
      #pragma unroll
      for (int m = 0; m < 4; ++m){
        const f32x16 c = (m < 2) ? s0 : s1;
        const int bx = (m & 1) * 8;
        unsigned A0 = cvt_pk(c[bx+0], c[bx+1]);
        unsigned B0 = cvt_pk(c[bx+4], c[bx+5]);
        pl32swap(A0, B0);
        unsigned A1 = cvt_pk(c[bx+2], c[bx+3]);
        unsigned B1 = cvt_pk(c[bx+6], c[bx+7]);
        pl32swap(A1, B1);
        u32x4 pw; pw.x = A0; pw.y = A1; pw.z = B0; pw.w = B1;
        const bf16x8 pa = __builtin_bit_cast(bf16x8, pw);
        bf16x8 vf0 = as_bf(*(const u16x8*)(Vp + koff[m]));
        y0 = __builtin_amdgcn_mfma_f32_32x32x16_bf16(pa, vf0, y0, 0, 0, 0);
        bf16x8 vf1 = as_bf(*(const u16x8*)(Vp + koff[m] + 2048));
        y1 = __builtin_amdgcn_mfma_f32_32x32x16_bf16(pa, vf1, y1, 0, 0, 0);
      }
      __builtin_amdgcn_s_setprio(0);
    }
    cb = nx;
  }

  const float linv = 1.f / l_;
  #pragma unroll
  for (int r = 0; r < 16; ++r){
    const int qlr = (r & 3) + 8*(r >> 2) + 4*hi;
    const float lr = __shfl(linv, qlr);
    unsigned short* yp = Y + ((size_t)b*TT + wq0 + qlr)*CC + h*DD + l31;
    yp[0]  = f2bf(y0[r] * lr);
    yp[32] = f2bf(y1[r] * lr);
  }
}

extern "C" void kernel_launch(void* const* d_in, const int* in_sizes, int n_in,
                              void* d_out, int out_size, void* d_ws, size_t ws_size,
                              hipStream_t stream){
  const float* x  = (const float*)d_in[0];
  const float* Wk = (const float*)d_in[1];
  const float* Wq = (const float*)d_in[2];
  const float* Wv = (const float*)d_in[3];
  const float* Wp = (const float*)d_in[4];

  const size_t E  = (size_t)BB*TT*CC;
  const size_t Wn = (size_t)CC*CC;
  unsigned short* ws  = (unsigned short*)d_ws;
  unsigned short* xb  = ws;                 // reused as yb after attention
  unsigned short* wkb = xb  + E;            // wkb,wqb,wvb contiguous = B[3072][1024]
  unsigned short* wqb = wkb + Wn;
  unsigned short* wvb = wqb + Wn;
  unsigned short* wpb = wvb + Wn;
  unsigned short* qb  = wpb + Wn;
  unsigned short* kb  = qb  + E;
  unsigned short* vb  = kb  + E;
  unsigned short* vt  = vb  + E;

  cvt_all<<<12288, 256, 0, stream>>>(x, Wk, Wq, Wv, Wp, xb, wkb);

  // fused QKV: B = [Wk; Wq; Wv] (3072x1024), outputs kb/qb/vb, Q scaled by log2e/8
  gemm128<24, true><<<dim3(24, 64), 256, 0, stream>>>(xb, wkb, kb, qb, vb);

  transpose_v<<<dim3(TT/64, BB*HH), 256, 0, stream>>>(vb, vt);

  unsigned short* yb = xb;
  attn2<<<dim3(BB*HH, TT/256), 512, 0, stream>>>(qb, kb, vt, yb);

  gemm128<8, false><<<dim3(8, 64), 256, 0, stream>>>(yb, wpb, (float*)d_out, nullptr, nullptr);
}

// Round 7
// 163.044 us; speedup vs baseline: 1.0867x; 1.0030x over previous
//
#include <hip/hip_runtime.h>

typedef __bf16 bf16x8 __attribute__((ext_vector_type(8)));
typedef float f32x4 __attribute__((ext_vector_type(4)));
typedef float f32x16 __attribute__((ext_vector_type(16)));
typedef unsigned short u16x8 __attribute__((ext_vector_type(8)));
typedef unsigned short u16x4 __attribute__((ext_vector_type(4)));
typedef unsigned u32x4 __attribute__((ext_vector_type(4)));

#define BB 4
#define TT 2048
#define CC 1024
#define HH 16
#define DD 64

__device__ __forceinline__ unsigned short f2bf(float f){
  unsigned u = __builtin_bit_cast(unsigned, f);
  u += 0x7FFFu + ((u >> 16) & 1u);
  return (unsigned short)(u >> 16);
}
__device__ __forceinline__ bf16x8 as_bf(u16x8 v){ return __builtin_bit_cast(bf16x8, v); }
__device__ __forceinline__ unsigned cvt_pk(float lo, float hi){
  unsigned r; asm("v_cvt_pk_bf16_f32 %0, %1, %2" : "=v"(r) : "v"(lo), "v"(hi)); return r;
}
__device__ __forceinline__ void pl32swap(unsigned &a, unsigned &b){
  asm("v_permlane32_swap_b32 %0, %1" : "+v"(a), "+v"(b));
}
__device__ __forceinline__ float ex2(float x){
#if __has_builtin(__builtin_amdgcn_exp2f)
  return __builtin_amdgcn_exp2f(x);
#else
  return __expf(x * 0.6931471805599453f);
#endif
}

// all 5 fp32->bf16 conversions in one launch
__global__ __launch_bounds__(256) void cvt_all(const float* __restrict__ x,
                                               const float* __restrict__ Wk,
                                               const float* __restrict__ Wq,
                                               const float* __restrict__ Wv,
                                               const float* __restrict__ Wp,
                                               unsigned short* __restrict__ xb,
                                               unsigned short* __restrict__ wb){
  const int i = blockIdx.x * 256 + threadIdx.x;           // one float4 per thread
  constexpr int EX = (BB*TT*CC)/4;                        // 2,097,152
  const float* src; unsigned short* dst; int off;
  if (i < EX){ src = x; dst = xb; off = i; }
  else {
    const int j = i - EX;
    const int wsel = j >> 18;                             // Wn/4 = 2^18
    off = j & 262143;
    src = (wsel==0) ? Wk : (wsel==1) ? Wq : (wsel==2) ? Wv : Wp;
    dst = wb + ((size_t)wsel << 20);                      // Wn = 2^20
  }
  const float4 f = ((const float4*)src)[off];
  u16x4 o; o.x = f2bf(f.x); o.y = f2bf(f.y); o.z = f2bf(f.z); o.w = f2bf(f.w);
  ((u16x4*)dst)[off] = o;
}

// C = A @ B^T, A: 8192xK row-major bf16, B: (NX*128)xK row-major bf16.
// R3-proven single-buffer 2-barrier structure (double-buffer regressed: occupancy).
// QKV=true: bf16 out into o0/o1/o2 (K,Q,V) with Q scaled by log2e/8. else f32 out o0.
template<int NX, bool QKV>
__global__ __launch_bounds__(256) void gemm128(const unsigned short* __restrict__ A,
                                               const unsigned short* __restrict__ Bm,
                                               void* __restrict__ o0, void* __restrict__ o1,
                                               void* __restrict__ o2){
  constexpr int K = 1024;
  constexpr int NWG = NX * 64;
  __shared__ __align__(16) unsigned short As[128*64];
  __shared__ __align__(16) unsigned short Bs[128*64];
  const int tid = threadIdx.x;
  const int flat = blockIdx.y * NX + blockIdx.x;
  const int swz = (flat & 7) * (NWG / 8) + (flat >> 3);   // bijective XCD swizzle
  const int n0 = (swz % NX) * 128;
  const int m0 = (swz / NX) * 128;
  const int w = tid >> 6, lane = tid & 63, l15 = lane & 15, g = lane >> 4;
  const int wm = (w >> 1) * 64, wn = (w & 1) * 64;

  f32x4 acc[4][4] = {};

  for (int k0 = 0; k0 < K; k0 += 64){
    #pragma unroll
    for (int i = 0; i < 4; ++i){
      const int p = i*256 + tid;
      const int r = p >> 3, c = p & 7;
      const int gc = c ^ (r & 7);
      __builtin_amdgcn_global_load_lds(
        (const __attribute__((address_space(1))) void*)(A + (size_t)(m0 + r)*K + k0 + gc*8),
        (__attribute__((address_space(3))) void*)(As + p*8), 16, 0, 0);
    }
    #pragma unroll
    for (int i = 0; i < 4; ++i){
      const int p = i*256 + tid;
      const int r = p >> 3, c = p & 7;
      const int gc = c ^ (r & 7);
      __builtin_amdgcn_global_load_lds(
        (const __attribute__((address_space(1))) void*)(Bm + (size_t)(n0 + r)*K + k0 + gc*8),
        (__attribute__((address_space(3))) void*)(Bs + p*8), 16, 0, 0);
    }
    __syncthreads();

    bf16x8 af[2][4], bfr[2][4];
    #pragma unroll
    for (int ks = 0; ks < 2; ++ks){
      #pragma unroll
      for (int m = 0; m < 4; ++m){
        const int R = wm + m*16 + l15;
        const int c = (ks*4 + g) ^ (R & 7);
        af[ks][m] = as_bf(*(const u16x8*)(As + R*64 + c*8));
      }
      #pragma unroll
      for (int n = 0; n < 4; ++n){
        const int R = wn + n*16 + l15;
        const int c = (ks*4 + g) ^ (R & 7);
        bfr[ks][n] = as_bf(*(const u16x8*)(Bs + R*64 + c*8));
      }
    }
    #pragma unroll
    for (int ks = 0; ks < 2; ++ks)
      #pragma unroll
      for (int m = 0; m < 4; ++m)
        #pragma unroll
        for (int n = 0; n < 4; ++n)
          acc[m][n] = __builtin_amdgcn_mfma_f32_16x16x32_bf16(af[ks][m], bfr[ks][n], acc[m][n], 0, 0, 0);
    __syncthreads();
  }

  const int tsel = n0 >> 10;                    // uniform per block (QKV only)
  const float sc = (QKV && tsel == 1) ? 0.18033688011112042f : 1.0f;  // log2(e)/8
  unsigned short* outb = nullptr;
  if (QKV) outb = (unsigned short*)(tsel == 0 ? o0 : tsel == 1 ? o1 : o2);

  #pragma unroll
  for (int m = 0; m < 4; ++m)
    #pragma unroll
    for (int n = 0; n < 4; ++n)
      #pragma unroll
      for (int r = 0; r < 4; ++r){
        const int row = m0 + wm + m*16 + g*4 + r;
        const int col = n0 + wn + n*16 + l15;
        const float v = acc[m][n][r];
        if (QKV) outb[(size_t)row*1024 + (col & 1023)] = f2bf(v * sc);
        else     ((float*)o0)[(size_t)row*1024 + col] = v;
      }
}

// V [B,T,C] (head slice) -> Vt [B*H][D][T], k-chunks XOR-swizzled within each 64-tile
__global__ __launch_bounds__(256) void transpose_v(const unsigned short* __restrict__ V,
                                                   unsigned short* __restrict__ Vt){
  __shared__ unsigned short Ts[64*72];
  const int kt = blockIdx.x, bh = blockIdx.y;
  const int b = bh >> 4, h = bh & 15;
  const int tid = threadIdx.x;
  #pragma unroll
  for (int i = 0; i < 2; ++i){
    const int p = i*256 + tid, r = p >> 3, c = p & 7;
    *(u16x8*)(Ts + r*72 + c*8) =
      *(const u16x8*)(V + (size_t)b*TT*CC + (size_t)(kt*64 + r)*CC + h*DD + c*8);
  }
  __syncthreads();
  #pragma unroll
  for (int i = 0; i < 2; ++i){
    const int p = i*256 + tid, d = p >> 3, c = p & 7;
    u16x8 v;
    #pragma unroll
    for (int j = 0; j < 8; ++j) v[j] = Ts[(c*8 + j)*72 + d];
    *(u16x8*)(Vt + ((size_t)bh*DD + d)*TT + (size_t)kt*64 + ((c ^ (d & 7))*8)) = v;
  }
}

// Causal flash attention, swapped-QK 32x32, 8 waves x 32 q-rows = 256 q-rows/block.
// KVBLK=128 (two stacked 64-subtiles), double-buffered, ONE barrier + vmcnt per tile.
// Q,K: [B,T,C] bf16 (Q pre-scaled by log2e/8); Vt: [B*H][D][T] swizzled; Y: [B,T,C] bf16
__global__ __launch_bounds__(512, 4) void attn2(const unsigned short* __restrict__ Q,
                                                const unsigned short* __restrict__ Km,
                                                const unsigned short* __restrict__ Vt,
                                                unsigned short* __restrict__ Y){
  __shared__ __align__(16) unsigned short Ks[2][8192];   // [buf][subtile(2)*4096]
  __shared__ __align__(16) unsigned short Vs[2][8192];
  const int bh = blockIdx.x, b = bh >> 4, h = bh & 15;
  const int yq = blockIdx.y;
  const int qt = (yq < 4) ? (7 - yq) : (yq - 4);  // pairs (7,0),(6,1),(5,2),(4,3) per CU
  const int tid = threadIdx.x;
  const int w = tid >> 6, lane = tid & 63, l31 = lane & 31, hi = lane >> 5;
  const int q0 = qt * 256;
  const int wq0 = q0 + w * 32;
  const int wqmax = wq0 + 31;
  const int nt = 2 * qt + 2;                      // 128-k tiles
  const int qg = wq0 + l31;

  const unsigned short* Ksrc = Km + (size_t)b*TT*CC + h*DD;
  const unsigned short* Vsrc = Vt + (size_t)bh*DD*TT;

  // stage one 128-k tile (two 64-k subtiles), 4 global_load_lds total
  auto stage = [&](int buf, int t){
    const int r = tid >> 3, c = tid & 7;
    const int gc = c ^ (r & 7);
    #pragma unroll
    for (int s = 0; s < 2; ++s){
      const int kt64 = 2*t + s;
      __builtin_amdgcn_global_load_lds(
        (const __attribute__((address_space(1))) void*)(Ksrc + (size_t)(kt64*64 + r)*CC + gc*8),
        (__attribute__((address_space(3))) void*)(&Ks[buf][s*4096 + tid*8]), 16, 0, 0);
      __builtin_amdgcn_global_load_lds(
        (const __attribute__((address_space(1))) void*)(Vsrc + (size_t)r*TT + (size_t)kt64*64 + c*8),
        (__attribute__((address_space(3))) void*)(&Vs[buf][s*4096 + tid*8]), 16, 0, 0);
    }
  };

  stage(0, 0);

  // Q fragments (B-operand): q = l31, d = 16*ds + 8*hi + j
  const unsigned short* qrow = Q + ((size_t)b*TT + wq0 + l31)*CC + h*DD;
  bf16x8 qf[4];
  #pragma unroll
  for (int ds = 0; ds < 4; ++ds)
    qf[ds] = as_bf(*(const u16x8*)(qrow + 16*ds + 8*hi));

  // LDS fragment offsets within a 64x64 subtile; +2048 for rows 32..63
  int koff[4];
  #pragma unroll
  for (int ds = 0; ds < 4; ++ds)
    koff[ds] = l31*64 + (((2*ds + hi) ^ (l31 & 7)) * 8);

  float m_ = -1e30f, l_ = 0.f;
  f32x16 y0 = {}, y1 = {};

  asm volatile("s_waitcnt vmcnt(0)" ::: "memory");
  __builtin_amdgcn_s_barrier();

  for (int t = 0; t < nt; ++t){
    const int cur = t & 1;
    if (t + 1 < nt) stage(cur ^ 1, t + 1);      // prefetch next tile (idle buffer)

    #pragma unroll
    for (int s = 0; s < 2; ++s){
      const int kb0 = t*128 + s*64;
      if (kb0 > wqmax) continue;                // fully-masked subtile
      const unsigned short* Kp = &Ks[cur][s*4096];
      const unsigned short* Vp = &Vs[cur][s*4096];

      // S^T = K . Q^T : lane holds q-col (l31), 32 k-rows across regs+hi
      f32x16 s0 = {}, s1 = {};
      __builtin_amdgcn_s_setprio(1);
      #pragma unroll
      for (int ds = 0; ds < 4; ++ds){
        bf16x8 kf0 = as_bf(*(const u16x8*)(Kp + koff[ds]));
        s0 = __builtin_amdgcn_mfma_f32_32x32x16_bf16(kf0, qf[ds], s0, 0, 0, 0);
        bf16x8 kf1 = as_bf(*(const u16x8*)(Kp + koff[ds] + 2048));
        s1 = __builtin_amdgcn_mfma_f32_32x32x16_bf16(kf1, qf[ds], s1, 0, 0, 0);
      }
      __builtin_amdgcn_s_setprio(0);

      if (kb0 + 63 > wq0){   // boundary subtile: causal mask (k_g > q_g)
        #pragma unroll
        for (int r = 0; r < 16; ++r){
          const int kr = (r & 3) + 8*(r >> 2) + 4*hi;
          if (kb0 + kr      > qg) s0[r] = -1e30f;
          if (kb0 + 32 + kr > qg) s1[r] = -1e30f;
        }
      }

      // tree max over 32 scores, then lane-pair merge
      float tm[8];
      #pragma unroll
      for (int r = 0; r < 8; ++r) tm[r] = fmaxf(fmaxf(s0[r], s0[r+8]), fmaxf(s1[r], s1[r+8]));
      #pragma unroll
      for (int r = 0; r < 4; ++r) tm[r] = fmaxf(tm[r], tm[r+4]);
      float pmax = fmaxf(fmaxf(tm[0], tm[2]), fmaxf(tm[1], tm[3]));
      pmax = fmaxf(pmax, __shfl_xor(pmax, 32));

      // defer-max rescale (log2 domain, THR=8 -> P <= 256)
      if (!__all(pmax <= m_ + 8.f)){
        const float mnew = fmaxf(m_, pmax);
        const float alpha = ex2(m_ - mnew);
        l_ *= alpha;
        #pragma unroll
        for (int r = 0; r < 16; ++r){
          const float ar = __shfl(alpha, (r & 3) + 8*(r >> 2) + 4*hi);
          y0[r] *= ar; y1[r] *= ar;
        }
        m_ = mnew;
      }

      #pragma unroll
      for (int r = 0; r < 16; ++r) s0[r] = ex2(s0[r] - m_);
      #pragma unroll
      for (int r = 0; r < 16; ++r) s1[r] = ex2(s1[r] - m_);
      float ts[8];
      #pragma unroll
      for (int r = 0; r < 8; ++r) ts[r] = (s0[r] + s0[r+8]) + (s1[r] + s1[r+8]);
      #pragma unroll
      for (int r = 0; r < 4; ++r) ts[r] += ts[r+4];
      float rs = (ts[0] + ts[2]) + (ts[1] + ts[3]);
      rs += __shfl_xor(rs, 32);
      l_ += rs;

      // P -> A-frags (cvt_pk + permlane32_swap), fused with PV MFMA
      __builtin_amdgcn_s_setprio(1);
      #pragma unroll
      for (int m = 0; m < 4; ++m){
        const f32x16 c = (m < 2) ? s0 : s1;
        const int bx = (m & 1) * 8;
        unsigned A0 = cvt_pk(c[bx+0], c[bx+1]);
        unsigned B0 = cvt_pk(c[bx+4], c[bx+5]);
        pl32swap(A0, B0);
        unsigned A1 = cvt_pk(c[bx+2], c[bx+3]);
        unsigned B1 = cvt_pk(c[bx+6], c[bx+7]);
        pl32swap(A1, B1);
        u32x4 pw; pw.x = A0; pw.y = A1; pw.z = B0; pw.w = B1;
        const bf16x8 pa = __builtin_bit_cast(bf16x8, pw);
        bf16x8 vf0 = as_bf(*(const u16x8*)(Vp + koff[m]));
        y0 = __builtin_amdgcn_mfma_f32_32x32x16_bf16(pa, vf0, y0, 0, 0, 0);
        bf16x8 vf1 = as_bf(*(const u16x8*)(Vp + koff[m] + 2048));
        y1 = __builtin_amdgcn_mfma_f32_32x32x16_bf16(pa, vf1, y1, 0, 0, 0);
      }
      __builtin_amdgcn_s_setprio(0);
    }

    if (t + 1 < nt){
      asm volatile("s_waitcnt vmcnt(0)" ::: "memory");   // next tile landed (hid under compute)
      __builtin_amdgcn_s_barrier();                      // all waves done reading cur
    }
  }

  const float linv = 1.f / l_;
  #pragma unroll
  for (int r = 0; r < 16; ++r){
    const int qlr = (r & 3) + 8*(r >> 2) + 4*hi;
    const float lr = __shfl(linv, qlr);
    unsigned short* yp = Y + ((size_t)b*TT + wq0 + qlr)*CC + h*DD + l31;
    yp[0]  = f2bf(y0[r] * lr);
    yp[32] = f2bf(y1[r] * lr);
  }
}

extern "C" void kernel_launch(void* const* d_in, const int* in_sizes, int n_in,
                              void* d_out, int out_size, void* d_ws, size_t ws_size,
                              hipStream_t stream){
  const float* x  = (const float*)d_in[0];
  const float* Wk = (const float*)d_in[1];
  const float* Wq = (const float*)d_in[2];
  const float* Wv = (const float*)d_in[3];
  const float* Wp = (const float*)d_in[4];

  const size_t E  = (size_t)BB*TT*CC;
  const size_t Wn = (size_t)CC*CC;
  unsigned short* ws  = (unsigned short*)d_ws;
  unsigned short* xb  = ws;                 // reused as yb after attention
  unsigned short* wkb = xb  + E;            // wkb,wqb,wvb contiguous = B[3072][1024]
  unsigned short* wqb = wkb + Wn;
  unsigned short* wvb = wqb + Wn;
  unsigned short* wpb = wvb + Wn;
  unsigned short* qb  = wpb + Wn;
  unsigned short* kb  = qb  + E;
  unsigned short* vb  = kb  + E;
  unsigned short* vt  = vb  + E;

  cvt_all<<<12288, 256, 0, stream>>>(x, Wk, Wq, Wv, Wp, xb, wkb);

  // fused QKV: B = [Wk; Wq; Wv] (3072x1024), outputs kb/qb/vb, Q scaled by log2e/8
  gemm128<24, true><<<dim3(24, 64), 256, 0, stream>>>(xb, wkb, kb, qb, vb);

  transpose_v<<<dim3(TT/64, BB*HH), 256, 0, stream>>>(vb, vt);

  unsigned short* yb = xb;
  attn2<<<dim3(BB*HH, TT/256), 512, 0, stream>>>(qb, kb, vt, yb);

  gemm128<8, false><<<dim3(8, 64), 256, 0, stream>>>(yb, wpb, (float*)d_out, nullptr, nullptr);
}

// Round 8
// 159.228 us; speedup vs baseline: 1.1127x; 1.0240x over previous
//
#include <hip/hip_runtime.h>

typedef __bf16 bf16x8 __attribute__((ext_vector_type(8)));
typedef float f32x4 __attribute__((ext_vector_type(4)));
typedef float f32x16 __attribute__((ext_vector_type(16)));
typedef unsigned short u16x8 __attribute__((ext_vector_type(8)));
typedef unsigned short u16x4 __attribute__((ext_vector_type(4)));
typedef unsigned u32x4 __attribute__((ext_vector_type(4)));

#define BB 4
#define TT 2048
#define CC 1024
#define HH 16
#define DD 64

__device__ __forceinline__ unsigned short f2bf(float f){
  unsigned u = __builtin_bit_cast(unsigned, f);
  u += 0x7FFFu + ((u >> 16) & 1u);
  return (unsigned short)(u >> 16);
}
__device__ __forceinline__ bf16x8 as_bf(u16x8 v){ return __builtin_bit_cast(bf16x8, v); }
__device__ __forceinline__ unsigned cvt_pk(float lo, float hi){
  unsigned r; asm("v_cvt_pk_bf16_f32 %0, %1, %2" : "=v"(r) : "v"(lo), "v"(hi)); return r;
}
__device__ __forceinline__ void pl32swap(unsigned &a, unsigned &b){
  asm("v_permlane32_swap_b32 %0, %1" : "+v"(a), "+v"(b));
}
__device__ __forceinline__ float ex2(float x){
#if __has_builtin(__builtin_amdgcn_exp2f)
  return __builtin_amdgcn_exp2f(x);
#else
  return __expf(x * 0.6931471805599453f);
#endif
}

// all 5 fp32->bf16 conversions in one launch
__global__ __launch_bounds__(256) void cvt_all(const float* __restrict__ x,
                                               const float* __restrict__ Wk,
                                               const float* __restrict__ Wq,
                                               const float* __restrict__ Wv,
                                               const float* __restrict__ Wp,
                                               unsigned short* __restrict__ xb,
                                               unsigned short* __restrict__ wb){
  const int i = blockIdx.x * 256 + threadIdx.x;           // one float4 per thread
  constexpr int EX = (BB*TT*CC)/4;                        // 2,097,152
  const float* src; unsigned short* dst; int off;
  if (i < EX){ src = x; dst = xb; off = i; }
  else {
    const int j = i - EX;
    const int wsel = j >> 18;                             // Wn/4 = 2^18
    off = j & 262143;
    src = (wsel==0) ? Wk : (wsel==1) ? Wq : (wsel==2) ? Wv : Wp;
    dst = wb + ((size_t)wsel << 20);                      // Wn = 2^20
  }
  const float4 f = ((const float4*)src)[off];
  u16x4 o; o.x = f2bf(f.x); o.y = f2bf(f.y); o.z = f2bf(f.z); o.w = f2bf(f.w);
  ((u16x4*)dst)[off] = o;
}

// C = A @ B^T, A: 8192xK row-major bf16, B: (NX*128)xK row-major bf16.
// Proven single-buffer 2-barrier structure.
// QKV=true: tsel 0 -> K rows to o0 (bf16), tsel 1 -> Q rows to o1 (bf16, *log2e/8),
//           tsel 2 -> V computed TRANSPOSED (swapped MFMA operands) and written
//           directly to o2 = Vt [B*H][D][T] with the attn XOR k-chunk swizzle.
// QKV=false: f32 out to o0.
template<int NX, bool QKV>
__global__ __launch_bounds__(256) void gemm128(const unsigned short* __restrict__ A,
                                               const unsigned short* __restrict__ Bm,
                                               void* __restrict__ o0, void* __restrict__ o1,
                                               void* __restrict__ o2){
  constexpr int K = 1024;
  constexpr int NWG = NX * 64;
  __shared__ __align__(16) unsigned short As[128*64];
  __shared__ __align__(16) unsigned short Bs[128*64];
  const int tid = threadIdx.x;
  const int flat = blockIdx.y * NX + blockIdx.x;
  const int swz = (flat & 7) * (NWG / 8) + (flat >> 3);   // bijective XCD swizzle
  const int n0 = (swz % NX) * 128;
  const int m0 = (swz / NX) * 128;
  const int w = tid >> 6, lane = tid & 63, l15 = lane & 15, g = lane >> 4;
  const int wm = (w >> 1) * 64, wn = (w & 1) * 64;
  const int tsel = QKV ? (n0 >> 10) : 0;                  // block-uniform

  f32x4 acc[4][4] = {};

  for (int k0 = 0; k0 < K; k0 += 64){
    #pragma unroll
    for (int i = 0; i < 4; ++i){
      const int p = i*256 + tid;
      const int r = p >> 3, c = p & 7;
      const int gc = c ^ (r & 7);
      __builtin_amdgcn_global_load_lds(
        (const __attribute__((address_space(1))) void*)(A + (size_t)(m0 + r)*K + k0 + gc*8),
        (__attribute__((address_space(3))) void*)(As + p*8), 16, 0, 0);
    }
    #pragma unroll
    for (int i = 0; i < 4; ++i){
      const int p = i*256 + tid;
      const int r = p >> 3, c = p & 7;
      const int gc = c ^ (r & 7);
      __builtin_amdgcn_global_load_lds(
        (const __attribute__((address_space(1))) void*)(Bm + (size_t)(n0 + r)*K + k0 + gc*8),
        (__attribute__((address_space(3))) void*)(Bs + p*8), 16, 0, 0);
    }
    __syncthreads();

    bf16x8 af[2][4], bfr[2][4];
    #pragma unroll
    for (int ks = 0; ks < 2; ++ks){
      #pragma unroll
      for (int m = 0; m < 4; ++m){
        const int R = wm + m*16 + l15;
        const int c = (ks*4 + g) ^ (R & 7);
        af[ks][m] = as_bf(*(const u16x8*)(As + R*64 + c*8));
      }
      #pragma unroll
      for (int n = 0; n < 4; ++n){
        const int R = wn + n*16 + l15;
        const int c = (ks*4 + g) ^ (R & 7);
        bfr[ks][n] = as_bf(*(const u16x8*)(Bs + R*64 + c*8));
      }
    }
    if (!QKV || tsel != 2){
      #pragma unroll
      for (int ks = 0; ks < 2; ++ks)
        #pragma unroll
        for (int m = 0; m < 4; ++m)
          #pragma unroll
          for (int n = 0; n < 4; ++n)
            acc[m][n] = __builtin_amdgcn_mfma_f32_16x16x32_bf16(af[ks][m], bfr[ks][n], acc[m][n], 0, 0, 0);
    } else {
      // V: compute C^T directly (swap operands). acc[n][m]: D-row = c-local, D-col = t-local
      #pragma unroll
      for (int ks = 0; ks < 2; ++ks)
        #pragma unroll
        for (int n = 0; n < 4; ++n)
          #pragma unroll
          for (int m = 0; m < 4; ++m)
            acc[n][m] = __builtin_amdgcn_mfma_f32_16x16x32_bf16(bfr[ks][n], af[ks][m], acc[n][m], 0, 0, 0);
    }
    __syncthreads();
  }

  if (QKV && tsel == 2){
    // write Vt [B*H][D][T] with XOR k-chunk swizzle (attn's expected layout)
    const int bq = m0 >> 11;                  // batch
    const int t0 = m0 & 2047;
    unsigned short* vt = (unsigned short*)o2;
    #pragma unroll
    for (int n = 0; n < 4; ++n)
      #pragma unroll
      for (int m = 0; m < 4; ++m)
        #pragma unroll
        for (int r = 0; r < 4; ++r){
          const int cg = (n0 & 1023) + wn + n*16 + g*4 + r;   // channel 0..1023
          const int h = cg >> 6, d = cg & 63;
          const int t = t0 + wm + m*16 + l15;
          const int kt = t >> 6, cch = (t >> 3) & 7, j = t & 7;
          const size_t idx = ((size_t)(bq*HH + h)*DD + d)*TT
                           + (size_t)kt*64 + ((cch ^ (d & 7)) << 3) + j;
          vt[idx] = f2bf(acc[n][m][r]);
        }
    return;
  }

  const float sc = (QKV && tsel == 1) ? 0.18033688011112042f : 1.0f;  // log2(e)/8
  unsigned short* outb = nullptr;
  if (QKV) outb = (unsigned short*)(tsel == 0 ? o0 : o1);

  #pragma unroll
  for (int m = 0; m < 4; ++m)
    #pragma unroll
    for (int n = 0; n < 4; ++n)
      #pragma unroll
      for (int r = 0; r < 4; ++r){
        const int row = m0 + wm + m*16 + g*4 + r;
        const int col = n0 + wn + n*16 + l15;
        const float v = acc[m][n][r];
        if (QKV) outb[(size_t)row*1024 + (col & 1023)] = f2bf(v * sc);
        else     ((float*)o0)[(size_t)row*1024 + col] = v;
      }
}

// Causal flash attention, swapped-QK 32x32, 8 waves x 32 q-rows = 256 q-rows/block.
// R6-proven: 3-buffer ring, counted vmcnt(2), balanced strip pairing.
// Q,K: [B,T,C] bf16 (Q pre-scaled by log2e/8); Vt: [B*H][D][T] swizzled; Y: [B,T,C] bf16
__global__ __launch_bounds__(512, 4) void attn2(const unsigned short* __restrict__ Q,
                                                const unsigned short* __restrict__ Km,
                                                const unsigned short* __restrict__ Vt,
                                                unsigned short* __restrict__ Y){
  __shared__ __align__(16) unsigned short Ks[3][64*64];
  __shared__ __align__(16) unsigned short Vs[3][64*64];
  const int bh = blockIdx.x, b = bh >> 4, h = bh & 15;
  const int yq = blockIdx.y;
  const int qt = (yq < 4) ? (7 - yq) : (yq - 4);  // pairs (7,0),(6,1),(5,2),(4,3) per CU
  const int tid = threadIdx.x;
  const int w = tid >> 6, lane = tid & 63, l31 = lane & 31, hi = lane >> 5;
  const int q0 = qt * 256;
  const int wq0 = q0 + w * 32;
  const int wqmax = wq0 + 31;
  const int nkt = 4 * qt + 4;
  const int qg = wq0 + l31;

  const unsigned short* Ksrc = Km + (size_t)b*TT*CC + h*DD;
  const unsigned short* Vsrc = Vt + (size_t)bh*DD*TT;

  auto stage = [&](int buf, int kt){
    const int r = tid >> 3, c = tid & 7;
    const int gc = c ^ (r & 7);
    __builtin_amdgcn_global_load_lds(
      (const __attribute__((address_space(1))) void*)(Ksrc + (size_t)(kt*64 + r)*CC + gc*8),
      (__attribute__((address_space(3))) void*)(&Ks[buf][tid*8]), 16, 0, 0);
    __builtin_amdgcn_global_load_lds(
      (const __attribute__((address_space(1))) void*)(Vsrc + (size_t)r*TT + (size_t)kt*64 + c*8),
      (__attribute__((address_space(3))) void*)(&Vs[buf][tid*8]), 16, 0, 0);
  };

  stage(0, 0);

  // Q fragments (B-operand): q = l31, d = 16*ds + 8*hi + j
  const unsigned short* qrow = Q + ((size_t)b*TT + wq0 + l31)*CC + h*DD;
  bf16x8 qf[4];
  #pragma unroll
  for (int ds = 0; ds < 4; ++ds)
    qf[ds] = as_bf(*(const u16x8*)(qrow + 16*ds + 8*hi));

  // LDS fragment offsets (elements); same for K and V tiles, +2048 for rows 32..63
  int koff[4];
  #pragma unroll
  for (int ds = 0; ds < 4; ++ds)
    koff[ds] = l31*64 + (((2*ds + hi) ^ (l31 & 7)) * 8);

  float m_ = -1e30f, l_ = 0.f;
  f32x16 y0 = {}, y1 = {};

  int cb = 0;
  for (int t = 0; t < nkt; ++t){
    const int nx = (cb == 2) ? 0 : cb + 1;
    if (t + 1 < nkt){
      stage(nx, t + 1);
      asm volatile("s_waitcnt vmcnt(2)" ::: "memory");
    } else {
      asm volatile("s_waitcnt vmcnt(0)" ::: "memory");
    }
    __builtin_amdgcn_s_barrier();

    if (t*64 <= wqmax){
      const unsigned short* Kp = &Ks[cb][0];
      const unsigned short* Vp = &Vs[cb][0];

      // S^T = K . Q^T : lane holds q-col (l31), 32 k-rows across regs+hi
      f32x16 s0 = {}, s1 = {};
      __builtin_amdgcn_s_setprio(1);
      #pragma unroll
      for (int ds = 0; ds < 4; ++ds){
        bf16x8 kf0 = as_bf(*(const u16x8*)(Kp + koff[ds]));
        s0 = __builtin_amdgcn_mfma_f32_32x32x16_bf16(kf0, qf[ds], s0, 0, 0, 0);
        bf16x8 kf1 = as_bf(*(const u16x8*)(Kp + koff[ds] + 2048));
        s1 = __builtin_amdgcn_mfma_f32_32x32x16_bf16(kf1, qf[ds], s1, 0, 0, 0);
      }
      __builtin_amdgcn_s_setprio(0);

      if (t*64 + 63 > wq0){   // boundary tiles: causal mask (k_g > q_g)
        const int kb0 = t*64;
        #pragma unroll
        for (int r = 0; r < 16; ++r){
          const int kr = (r & 3) + 8*(r >> 2) + 4*hi;
          if (kb0 + kr      > qg) s0[r] = -1e30f;
          if (kb0 + 32 + kr > qg) s1[r] = -1e30f;
        }
      }

      // tree max over 32 scores, then lane-pair merge
      float tm[8];
      #pragma unroll
      for (int r = 0; r < 8; ++r) tm[r] = fmaxf(fmaxf(s0[r], s0[r+8]), fmaxf(s1[r], s1[r+8]));
      #pragma unroll
      for (int r = 0; r < 4; ++r) tm[r] = fmaxf(tm[r], tm[r+4]);
      float pmax = fmaxf(fmaxf(tm[0], tm[2]), fmaxf(tm[1], tm[3]));
      pmax = fmaxf(pmax, __shfl_xor(pmax, 32));

      // defer-max rescale (log2 domain, THR=8 -> P <= 256)
      if (!__all(pmax <= m_ + 8.f)){
        const float mnew = fmaxf(m_, pmax);
        const float alpha = ex2(m_ - mnew);
        l_ *= alpha;
        #pragma unroll
        for (int r = 0; r < 16; ++r){
          const float ar = __shfl(alpha, (r & 3) + 8*(r >> 2) + 4*hi);
          y0[r] *= ar; y1[r] *= ar;
        }
        m_ = mnew;
      }

      #pragma unroll
      for (int r = 0; r < 16; ++r) s0[r] = ex2(s0[r] - m_);
      #pragma unroll
      for (int r = 0; r < 16; ++r) s1[r] = ex2(s1[r] - m_);
      float ts[8];
      #pragma unroll
      for (int r = 0; r < 8; ++r) ts[r] = (s0[r] + s0[r+8]) + (s1[r] + s1[r+8]);
      #pragma unroll
      for (int r = 0; r < 4; ++r) ts[r] += ts[r+4];
      float rs = (ts[0] + ts[2]) + (ts[1] + ts[3]);
      rs += __shfl_xor(rs, 32);
      l_ += rs;

      // P -> A-frags (cvt_pk + permlane32_swap), fused with PV MFMA
      __builtin_amdgcn_s_setprio(1);
      #pragma unroll
      for (int m = 0; m < 4; ++m){
        const f32x16 c = (m < 2) ? s0 : s1;
        const int bx = (m & 1) * 8;
        unsigned A0 = cvt_pk(c[bx+0], c[bx+1]);
        unsigned B0 = cvt_pk(c[bx+4], c[bx+5]);
        pl32swap(A0, B0);
        unsigned A1 = cvt_pk(c[bx+2], c[bx+3]);
        unsigned B1 = cvt_pk(c[bx+6], c[bx+7]);
        pl32swap(A1, B1);
        u32x4 pw; pw.x = A0; pw.y = A1; pw.z = B0; pw.w = B1;
        const bf16x8 pa = __builtin_bit_cast(bf16x8, pw);
        bf16x8 vf0 = as_bf(*(const u16x8*)(Vp + koff[m]));
        y0 = __builtin_amdgcn_mfma_f32_32x32x16_bf16(pa, vf0, y0, 0, 0, 0);
        bf16x8 vf1 = as_bf(*(const u16x8*)(Vp + koff[m] + 2048));
        y1 = __builtin_amdgcn_mfma_f32_32x32x16_bf16(pa, vf1, y1, 0, 0, 0);
      }
      __builtin_amdgcn_s_setprio(0);
    }
    cb = nx;
  }

  const float linv = 1.f / l_;
  #pragma unroll
  for (int r = 0; r < 16; ++r){
    const int qlr = (r & 3) + 8*(r >> 2) + 4*hi;
    const float lr = __shfl(linv, qlr);
    unsigned short* yp = Y + ((size_t)b*TT + wq0 + qlr)*CC + h*DD + l31;
    yp[0]  = f2bf(y0[r] * lr);
    yp[32] = f2bf(y1[r] * lr);
  }
}

extern "C" void kernel_launch(void* const* d_in, const int* in_sizes, int n_in,
                              void* d_out, int out_size, void* d_ws, size_t ws_size,
                              hipStream_t stream){
  const float* x  = (const float*)d_in[0];
  const float* Wk = (const float*)d_in[1];
  const float* Wq = (const float*)d_in[2];
  const float* Wv = (const float*)d_in[3];
  const float* Wp = (const float*)d_in[4];

  const size_t E  = (size_t)BB*TT*CC;
  const size_t Wn = (size_t)CC*CC;
  unsigned short* ws  = (unsigned short*)d_ws;
  unsigned short* xb  = ws;                 // reused as yb after attention
  unsigned short* wkb = xb  + E;            // wkb,wqb,wvb contiguous = B[3072][1024]
  unsigned short* wqb = wkb + Wn;
  unsigned short* wvb = wqb + Wn;
  unsigned short* wpb = wvb + Wn;
  unsigned short* qb  = wpb + Wn;
  unsigned short* kb  = qb  + E;
  unsigned short* vt  = kb  + E;            // V written transposed by QKV GEMM

  cvt_all<<<12288, 256, 0, stream>>>(x, Wk, Wq, Wv, Wp, xb, wkb);

  // fused QKV: B = [Wk; Wq; Wv] (3072x1024) -> kb, qb (scaled), vt (transposed+swizzled)
  gemm128<24, true><<<dim3(24, 64), 256, 0, stream>>>(xb, wkb, kb, qb, vt);

  unsigned short* yb = xb;
  attn2<<<dim3(BB*HH, TT/256), 512, 0, stream>>>(qb, kb, vt, yb);

  gemm128<8, false><<<dim3(8, 64), 256, 0, stream>>>(yb, wpb, (float*)d_out, nullptr, nullptr);
}